// Round 6
// baseline (170.832 us; speedup 1.0000x reference)
//
#include <hip/hip_runtime.h>
#include <hip/hip_bf16.h>

// B=8, S=2048, H=512. out[b,i,:] = sum_{j<i} exp(q_i.x_j) x_j / (sum_{j<i} exp(q_i.x_j) + 1e-10)
// q = X @ W^T + b.
// R6: 3-GEMM structure (R5) + min-2-phase prefetch (double-buffered LDS, 1 barrier/K-step)
//     + split-K pvgemm (balanced 640-block grid, atomicAdd partials, divide kernel).
#define BATCH 8
#define SEQ   2048
#define DIM   512

typedef __bf16 bf16x8 __attribute__((ext_vector_type(8)));
typedef float  f32x4  __attribute__((ext_vector_type(4)));

__device__ __forceinline__ ushort f2bf(float f) {
    union { float f; unsigned u; } c; c.f = f;
    unsigned u = c.u;
    u += 0x7fffu + ((u >> 16) & 1u);   // round-to-nearest-even
    return (ushort)(u >> 16);
}

// ---------------- prep: X f32 -> Xb bf16 (row-major) + Xt bf16 (transposed [b][h][s]) ---------
__global__ __launch_bounds__(256) void prep_kernel(const float* __restrict__ X,
                                                   ushort* __restrict__ Xb,
                                                   ushort* __restrict__ Xt) {
    __shared__ ushort T[32 * 33];
    int t   = threadIdx.x;
    int bid = blockIdx.x;              // 8 * 64 * 16 = 8192
    int b   = bid >> 10;
    int st  = (bid >> 4) & 63;
    int ht  = bid & 15;
    int s0 = st * 32, h0 = ht * 32;

    int r  = t >> 3;                   // 0..31 (s within tile)
    int c4 = (t & 7) * 4;              // 0..28 (h within tile)
    size_t src = ((size_t)(b * SEQ + s0 + r)) * DIM + h0 + c4;
    float4 v = *(const float4*)(X + src);
    ushort u0 = f2bf(v.x), u1 = f2bf(v.y), u2 = f2bf(v.z), u3 = f2bf(v.w);
    ushort4 uv; uv.x = u0; uv.y = u1; uv.z = u2; uv.w = u3;
    *(ushort4*)(Xb + src) = uv;
    T[(c4 + 0) * 33 + r] = u0;
    T[(c4 + 1) * 33 + r] = u1;
    T[(c4 + 2) * 33 + r] = u2;
    T[(c4 + 3) * 33 + r] = u3;
    __syncthreads();
    int hh = t >> 3;                   // 0..31 (h)
    int sc = (t & 7) * 4;              // 0..28 (s)
    ushort4 w;
    w.x = T[hh * 33 + sc + 0];
    w.y = T[hh * 33 + sc + 1];
    w.z = T[hh * 33 + sc + 2];
    w.w = T[hh * 33 + sc + 3];
    *(ushort4*)(Xt + ((size_t)(b * DIM + h0 + hh)) * SEQ + s0 + sc) = w;
}

// ---------------- wconv: W f32 -> bf16 ----------------
__global__ __launch_bounds__(256) void wconv_kernel(const float* __restrict__ W,
                                                    ushort* __restrict__ Wb) {
    int gt = blockIdx.x * 256 + threadIdx.x;   // 128 blocks, 8 elems each
    size_t base = (size_t)gt * 8;
    float4 a = *(const float4*)(W + base);
    float4 c = *(const float4*)(W + base + 4);
    ushort4 lo, hi;
    lo.x = f2bf(a.x); lo.y = f2bf(a.y); lo.z = f2bf(a.z); lo.w = f2bf(a.w);
    hi.x = f2bf(c.x); hi.y = f2bf(c.y); hi.z = f2bf(c.z); hi.w = f2bf(c.w);
    *(ushort4*)(Wb + base)     = lo;
    *(ushort4*)(Wb + base + 4) = hi;
}

// Shared 2-phase GEMM body pieces (At/Bt double-buffered, pitch 40 shorts = 80B, 16B-aligned)
#define GEMM_COMPUTE(CUR)                                                                  \
    {                                                                                      \
        bf16x8 af[4], bfr[4];                                                              \
        _Pragma("unroll") for (int r = 0; r < 4; ++r)                                      \
            af[r] = *(const bf16x8*)&At[CUR][(wr * 64 + r * 16 + ln) * 40 + lg * 8];       \
        _Pragma("unroll") for (int cc = 0; cc < 4; ++cc)                                   \
            bfr[cc] = *(const bf16x8*)&Bt[CUR][(wc * 64 + cc * 16 + ln) * 40 + lg * 8];    \
        _Pragma("unroll") for (int r = 0; r < 4; ++r)                                      \
            _Pragma("unroll") for (int cc = 0; cc < 4; ++cc)                               \
                acc[r][cc] = __builtin_amdgcn_mfma_f32_16x16x32_bf16(af[r], bfr[cc],       \
                                                                     acc[r][cc], 0, 0, 0); \
    }

#define GEMM_STORE(CUR, A0, A1, B0, B1)                   \
    {                                                     \
        *(uint4*)&At[CUR][srow * 40 + sc8]        = A0;   \
        *(uint4*)&At[CUR][(64 + srow) * 40 + sc8] = A1;   \
        *(uint4*)&Bt[CUR][srow * 40 + sc8]        = B0;   \
        *(uint4*)&Bt[CUR][(64 + srow) * 40 + sc8] = B1;   \
    }

// ---------------- qgemm: Qb = bf16(Xb @ Wb^T + bias), 2-phase ----------------
__global__ __launch_bounds__(256, 2) void qgemm_kernel(const ushort* __restrict__ Xb,
                                                       const ushort* __restrict__ Wb,
                                                       const float* __restrict__ bias,
                                                       ushort* __restrict__ Qb) {
    __shared__ ushort At[2][128 * 40];
    __shared__ ushort Bt[2][128 * 40];
    int t   = threadIdx.x;
    int bid = blockIdx.x;              // 128 mtiles * 4 ntiles
    int mt = bid >> 2, nt = bid & 3;
    int m0 = mt << 7, n0 = nt << 7;
    int w  = t >> 6, l = t & 63, ln = l & 15, lg = l >> 4;
    int wr = w >> 1, wc = w & 1;

    f32x4 acc[4][4] = {};
    int srow = t >> 2;
    int sc8  = (t & 3) * 8;

    const ushort* Arow = Xb + (size_t)m0 * 512;
    const ushort* Brow = Wb + (size_t)n0 * 512;

#define QG_LOAD(KS, A0, A1, B0, B1)                                                \
    A0 = *(const uint4*)(Arow + (size_t)srow * 512 + (KS) * 32 + sc8);             \
    A1 = *(const uint4*)(Arow + (size_t)(64 + srow) * 512 + (KS) * 32 + sc8);      \
    B0 = *(const uint4*)(Brow + (size_t)srow * 512 + (KS) * 32 + sc8);             \
    B1 = *(const uint4*)(Brow + (size_t)(64 + srow) * 512 + (KS) * 32 + sc8);

    uint4 a0, a1, b0, b1;
    QG_LOAD(0, a0, a1, b0, b1)
    GEMM_STORE(0, a0, a1, b0, b1)
    __syncthreads();
    int cur = 0;
    for (int ks = 0; ks < 15; ++ks) {
        uint4 na0, na1, nb0, nb1;
        QG_LOAD(ks + 1, na0, na1, nb0, nb1)
        GEMM_COMPUTE(cur)
        GEMM_STORE(cur ^ 1, na0, na1, nb0, nb1)
        __syncthreads();
        cur ^= 1;
    }
    GEMM_COMPUTE(cur)

    float bv[4];
#pragma unroll
    for (int c = 0; c < 4; ++c) bv[c] = bias[n0 + wc * 64 + c * 16 + ln];
#pragma unroll
    for (int r = 0; r < 4; ++r)
#pragma unroll
        for (int c = 0; c < 4; ++c)
#pragma unroll
            for (int q = 0; q < 4; ++q) {
                int row = m0 + wr * 64 + r * 16 + lg * 4 + q;
                int col = n0 + wc * 64 + c * 16 + ln;
                Qb[(size_t)row * 512 + col] = f2bf(acc[r][c][q] + bv[c]);
            }
}

// ---------------- sgemm: P = exp(mask(Q X^T)) packed lower-tri tiles + rowsum->den, 2-phase ---
__global__ __launch_bounds__(256, 2) void sgemm_kernel(const ushort* __restrict__ Qb,
                                                       const ushort* __restrict__ Xb,
                                                       ushort* __restrict__ Pb,
                                                       float* __restrict__ den,
                                                       int g0, int G) {
    __shared__ ushort At[2][128 * 40];
    __shared__ ushort Bt[2][128 * 40];
    int t  = threadIdx.x;
    int bL = blockIdx.x;
    int b  = g0 + bL;
    int c  = blockIdx.y;               // 0..135
    int it = 0, base = 0;
    for (;;) { if (c < base + it + 1) break; base += it + 1; ++it; }
    int jt = c - base;

    int m0 = it << 7, n0 = jt << 7;
    int w  = t >> 6, l = t & 63, ln = l & 15, lg = l >> 4;
    int wr = w >> 1, wc = w & 1;

    const ushort* Arow = Qb + (size_t)(b * SEQ + m0) * 512;
    const ushort* Brow = Xb + (size_t)(b * SEQ + n0) * 512;

    f32x4 acc[4][4] = {};
    int srow = t >> 2;
    int sc8  = (t & 3) * 8;

#define SG_LOAD(KS, A0, A1, B0, B1)                                                \
    A0 = *(const uint4*)(Arow + (size_t)srow * 512 + (KS) * 32 + sc8);             \
    A1 = *(const uint4*)(Arow + (size_t)(64 + srow) * 512 + (KS) * 32 + sc8);      \
    B0 = *(const uint4*)(Brow + (size_t)srow * 512 + (KS) * 32 + sc8);             \
    B1 = *(const uint4*)(Brow + (size_t)(64 + srow) * 512 + (KS) * 32 + sc8);

    uint4 a0, a1, b0, b1;
    SG_LOAD(0, a0, a1, b0, b1)
    GEMM_STORE(0, a0, a1, b0, b1)
    __syncthreads();
    int cur = 0;
    for (int ks = 0; ks < 15; ++ks) {
        uint4 na0, na1, nb0, nb1;
        SG_LOAD(ks + 1, na0, na1, nb0, nb1)
        GEMM_COMPUTE(cur)
        GEMM_STORE(cur ^ 1, na0, na1, nb0, nb1)
        __syncthreads();
        cur ^= 1;
    }
    GEMM_COMPUTE(cur)

    ushort* ptile = Pb + ((size_t)c * G + bL) * 16384;
#pragma unroll
    for (int r = 0; r < 4; ++r)
#pragma unroll
        for (int q = 0; q < 4; ++q) {
            int row  = wr * 64 + r * 16 + lg * 4 + q;       // local i
            int grow = m0 + row;                            // in-batch i
            float rs = 0.f;
#pragma unroll
            for (int cc = 0; cc < 4; ++cc) {
                int col = n0 + wc * 64 + cc * 16 + ln;      // in-batch j
                float ex = (col < grow) ? __expf(acc[r][cc][q]) : 0.f;
                rs += ex;
                ptile[row * 128 + (wc * 64 + cc * 16 + ln)] = f2bf(ex);
            }
            rs += __shfl_xor(rs, 1);
            rs += __shfl_xor(rs, 2);
            rs += __shfl_xor(rs, 4);
            rs += __shfl_xor(rs, 8);
            if (ln == 0) unsafeAtomicAdd(&den[b * SEQ + grow], rs);
        }
}

// ---------------- pvgemm: out += P @ X (split-K, atomic), 2-phase -----------------------------
// blockIdx.y in [0,160): it descending (heavy first); per it: 4 ht x ceil((it+1)/4) chunks.
// Chunk = up to 16 K-steps (4 P-tiles of 128).
__global__ __launch_bounds__(256, 2) void pvgemm_kernel(const ushort* __restrict__ Pb,
                                                        const ushort* __restrict__ Xt,
                                                        float* __restrict__ out,
                                                        int g0, int G) {
    __shared__ ushort At[2][128 * 40];
    __shared__ ushort Bt[2][128 * 40];
    int t  = threadIdx.x;
    int bL = blockIdx.x;
    int b  = g0 + bL;

    int rem = blockIdx.y, it = 15;
    for (;;) { int n = ((it + 4) >> 2) * 4; if (rem < n) break; rem -= n; --it; }
    int cit = (it + 4) >> 2;
    int ht = 0;
    while (rem >= cit) { rem -= cit; ++ht; }
    int ck = rem;
    int k0 = ck * 16;
    int k1 = min(k0 + 16, (it + 1) * 4);
    int nks = k1 - k0;
    int Tit = (it * (it + 1)) >> 1;

    int m0 = it << 7, n0 = ht << 7;
    int w  = t >> 6, l = t & 63, ln = l & 15, lg = l >> 4;
    int wr = w >> 1, wc = w & 1;

    const ushort* BrowX = Xt + (size_t)(b * DIM + n0) * SEQ;

    f32x4 acc[4][4] = {};
    int srow = t >> 2;
    int sc8  = (t & 3) * 8;

#define PV_LOAD(KK, A0, A1, B0, B1)                                                         \
    {                                                                                       \
        const ushort* ptile = Pb + ((size_t)(Tit + ((KK) >> 2)) * G + bL) * 16384           \
                              + ((KK) & 3) * 32;                                            \
        A0 = *(const uint4*)(ptile + srow * 128 + sc8);                                     \
        A1 = *(const uint4*)(ptile + (64 + srow) * 128 + sc8);                              \
        B0 = *(const uint4*)(BrowX + (size_t)srow * SEQ + (KK) * 32 + sc8);                 \
        B1 = *(const uint4*)(BrowX + (size_t)(64 + srow) * SEQ + (KK) * 32 + sc8);          \
    }

    uint4 a0, a1, b0, b1;
    PV_LOAD(k0, a0, a1, b0, b1)
    GEMM_STORE(0, a0, a1, b0, b1)
    __syncthreads();
    int cur = 0;
    for (int ks = 0; ks < nks - 1; ++ks) {
        uint4 na0, na1, nb0, nb1;
        PV_LOAD(k0 + ks + 1, na0, na1, nb0, nb1)
        GEMM_COMPUTE(cur)
        GEMM_STORE(cur ^ 1, na0, na1, nb0, nb1)
        __syncthreads();
        cur ^= 1;
    }
    GEMM_COMPUTE(cur)

#pragma unroll
    for (int r = 0; r < 4; ++r)
#pragma unroll
        for (int q = 0; q < 4; ++q) {
            size_t grow = (size_t)(b * SEQ + m0 + wr * 64 + r * 16 + lg * 4 + q) * 512;
#pragma unroll
            for (int cc = 0; cc < 4; ++cc)
                unsafeAtomicAdd(&out[grow + n0 + wc * 64 + cc * 16 + ln], acc[r][cc][q]);
        }
}

// ---------------- divide: out = out / (den + 1e-10) ----------------
__global__ __launch_bounds__(256) void divide_kernel(float* __restrict__ num,
                                                     const float* __restrict__ den) {
    int idx = blockIdx.x * 256 + threadIdx.x;      // 8192 blocks -> 2,097,152 float4
    float4 v = ((const float4*)num)[idx];
    int row = idx >> 7;                            // 128 float4 per 512-col row
    float inv = 1.0f / (den[row] + 1e-10f);
    v.x *= inv; v.y *= inv; v.z *= inv; v.w *= inv;
    ((float4*)num)[idx] = v;
}

extern "C" void kernel_launch(void* const* d_in, const int* in_sizes, int n_in,
                              void* d_out, int out_size, void* d_ws, size_t ws_size,
                              hipStream_t stream) {
    const float* X    = (const float*)d_in[0];
    const float* W    = (const float*)d_in[1];
    const float* bias = (const float*)d_in[2];
    float* out = (float*)d_out;

    // ws layout (bytes): Xb[16.78M] | Xt[16.78M] | Qb[16.78M] | Wb[0.52M] | den[64K] | Pb[G*4.46M]
    ushort* ws = (ushort*)d_ws;
    ushort* Xb = ws;
    ushort* Xt = ws + 8388608;
    ushort* Qb = ws + 16777216;
    ushort* Wb = ws + 25165824;
    float*  den = (float*)((char*)d_ws + 50855936);
    ushort* Pb = (ushort*)((char*)d_ws + 50921472);

    // batch-group size: largest pow2 G<=8 with Pb (G*4,456,448 B) fitting in remaining ws
    size_t avail = (ws_size > 50921472) ? (ws_size - 50921472) : 0;
    int G = 1;
    while (G < 8 && (size_t)(G * 2) * 4456448 <= avail) G *= 2;

    hipMemsetAsync(den, 0, (size_t)BATCH * SEQ * sizeof(float), stream);
    hipMemsetAsync(out, 0, (size_t)BATCH * SEQ * DIM * sizeof(float), stream);
    prep_kernel<<<dim3(8192), dim3(256), 0, stream>>>(X, Xb, Xt);
    wconv_kernel<<<dim3(128), dim3(256), 0, stream>>>(W, Wb);
    qgemm_kernel<<<dim3(512), dim3(256), 0, stream>>>(Xb, Wb, bias, Qb);
    for (int g0 = 0; g0 < BATCH; g0 += G) {
        sgemm_kernel<<<dim3(G, 136), dim3(256), 0, stream>>>(Qb, Xb, Pb, den, g0, G);
        pvgemm_kernel<<<dim3(G, 160), dim3(256), 0, stream>>>(Pb, Xt, out, g0, G);
    }
    divide_kernel<<<dim3(8192), dim3(256), 0, stream>>>(out, den);
}

// Round 7
// 109.874 us; speedup vs baseline: 1.5548x; 1.5548x over previous
//
#include <hip/hip_runtime.h>
#include <hip/hip_bf16.h>

// B=8, S=2048, H=512. out[b,i,:] = sum_{j<i} exp(q_i.x_j) x_j / (sum_{j<i} exp(q_i.x_j) + 1e-10)
// q = X @ W^T + b.
// R7: 3-GEMM structure; depth-2 register pipeline (2 reg sets + 2 LDS bufs, 1 barrier/K-step);
//     pvgemm reverted to full-K ownership (no atomics/memset/divide), balanced via it-pairing
//     (block does tiles it=15-p and it=p -> uniform 68 K-steps), N-tile 64 -> 512 uniform blocks.
#define BATCH 8
#define SEQ   2048
#define DIM   512

typedef __bf16 bf16x8 __attribute__((ext_vector_type(8)));
typedef float  f32x4  __attribute__((ext_vector_type(4)));

__device__ __forceinline__ ushort f2bf(float f) {
    union { float f; unsigned u; } c; c.f = f;
    unsigned u = c.u;
    u += 0x7fffu + ((u >> 16) & 1u);   // round-to-nearest-even
    return (ushort)(u >> 16);
}

// ---------------- prep: X f32 -> Xb bf16 (row-major) + Xt bf16 (transposed [b][h][s]) ---------
__global__ __launch_bounds__(256) void prep_kernel(const float* __restrict__ X,
                                                   ushort* __restrict__ Xb,
                                                   ushort* __restrict__ Xt) {
    __shared__ ushort T[32 * 33];
    int t   = threadIdx.x;
    int bid = blockIdx.x;              // 8 * 64 * 16 = 8192
    int b   = bid >> 10;
    int st  = (bid >> 4) & 63;
    int ht  = bid & 15;
    int s0 = st * 32, h0 = ht * 32;

    int r  = t >> 3;                   // 0..31 (s within tile)
    int c4 = (t & 7) * 4;              // 0..28 (h within tile)
    size_t src = ((size_t)(b * SEQ + s0 + r)) * DIM + h0 + c4;
    float4 v = *(const float4*)(X + src);
    ushort u0 = f2bf(v.x), u1 = f2bf(v.y), u2 = f2bf(v.z), u3 = f2bf(v.w);
    ushort4 uv; uv.x = u0; uv.y = u1; uv.z = u2; uv.w = u3;
    *(ushort4*)(Xb + src) = uv;
    T[(c4 + 0) * 33 + r] = u0;
    T[(c4 + 1) * 33 + r] = u1;
    T[(c4 + 2) * 33 + r] = u2;
    T[(c4 + 3) * 33 + r] = u3;
    __syncthreads();
    int hh = t >> 3;                   // 0..31 (h)
    int sc = (t & 7) * 4;              // 0..28 (s)
    ushort4 w;
    w.x = T[hh * 33 + sc + 0];
    w.y = T[hh * 33 + sc + 1];
    w.z = T[hh * 33 + sc + 2];
    w.w = T[hh * 33 + sc + 3];
    *(ushort4*)(Xt + ((size_t)(b * DIM + h0 + hh)) * SEQ + s0 + sc) = w;
}

// ---------------- wconv: W f32 -> bf16 ----------------
__global__ __launch_bounds__(256) void wconv_kernel(const float* __restrict__ W,
                                                    ushort* __restrict__ Wb) {
    int gt = blockIdx.x * 256 + threadIdx.x;   // 128 blocks, 8 elems each
    size_t base = (size_t)gt * 8;
    float4 a = *(const float4*)(W + base);
    float4 c = *(const float4*)(W + base + 4);
    ushort4 lo, hi;
    lo.x = f2bf(a.x); lo.y = f2bf(a.y); lo.z = f2bf(a.z); lo.w = f2bf(a.w);
    hi.x = f2bf(c.x); hi.y = f2bf(c.y); hi.z = f2bf(c.z); hi.w = f2bf(c.w);
    *(ushort4*)(Wb + base)     = lo;
    *(ushort4*)(Wb + base + 4) = hi;
}

// Shared 128x128-tile pieces (At/Bt double-buffered, pitch 40 shorts = 80B, 16B-aligned)
#define GEMM_COMPUTE(CUR)                                                                  \
    {                                                                                      \
        bf16x8 af[4], bfr[4];                                                              \
        _Pragma("unroll") for (int r = 0; r < 4; ++r)                                      \
            af[r] = *(const bf16x8*)&At[CUR][(wr * 64 + r * 16 + ln) * 40 + lg * 8];       \
        _Pragma("unroll") for (int cc = 0; cc < 4; ++cc)                                   \
            bfr[cc] = *(const bf16x8*)&Bt[CUR][(wc * 64 + cc * 16 + ln) * 40 + lg * 8];    \
        _Pragma("unroll") for (int r = 0; r < 4; ++r)                                      \
            _Pragma("unroll") for (int cc = 0; cc < 4; ++cc)                               \
                acc[r][cc] = __builtin_amdgcn_mfma_f32_16x16x32_bf16(af[r], bfr[cc],       \
                                                                     acc[r][cc], 0, 0, 0); \
    }

#define GEMM_STORE(CUR, A0, A1, B0, B1)                   \
    {                                                     \
        *(uint4*)&At[CUR][srow * 40 + sc8]        = A0;   \
        *(uint4*)&At[CUR][(64 + srow) * 40 + sc8] = A1;   \
        *(uint4*)&Bt[CUR][srow * 40 + sc8]        = B0;   \
        *(uint4*)&Bt[CUR][(64 + srow) * 40 + sc8] = B1;   \
    }

// ---------------- qgemm: Qb = bf16(Xb @ Wb^T + bias), depth-2 pipeline ----------------
__global__ __launch_bounds__(256, 2) void qgemm_kernel(const ushort* __restrict__ Xb,
                                                       const ushort* __restrict__ Wb,
                                                       const float* __restrict__ bias,
                                                       ushort* __restrict__ Qb) {
    __shared__ ushort At[2][128 * 40];
    __shared__ ushort Bt[2][128 * 40];
    int t   = threadIdx.x;
    int bid = blockIdx.x;              // 128 mtiles * 4 ntiles
    int mt = bid >> 2, nt = bid & 3;
    int m0 = mt << 7, n0 = nt << 7;
    int w  = t >> 6, l = t & 63, ln = l & 15, lg = l >> 4;
    int wr = w >> 1, wc = w & 1;

    f32x4 acc[4][4] = {};
    int srow = t >> 2;
    int sc8  = (t & 3) * 8;

    const ushort* Arow = Xb + (size_t)m0 * 512;
    const ushort* Brow = Wb + (size_t)n0 * 512;

#define QG_LOAD(KS, A0, A1, B0, B1)                                                \
    A0 = *(const uint4*)(Arow + (size_t)srow * 512 + (KS) * 32 + sc8);             \
    A1 = *(const uint4*)(Arow + (size_t)(64 + srow) * 512 + (KS) * 32 + sc8);      \
    B0 = *(const uint4*)(Brow + (size_t)srow * 512 + (KS) * 32 + sc8);             \
    B1 = *(const uint4*)(Brow + (size_t)(64 + srow) * 512 + (KS) * 32 + sc8);

    uint4 pA0, pA1, pB0, pB1, qA0, qA1, qB0, qB1;
    QG_LOAD(0, pA0, pA1, pB0, pB1)
    QG_LOAD(1, qA0, qA1, qB0, qB1)
    GEMM_STORE(0, pA0, pA1, pB0, pB1)
    __syncthreads();
    for (int ks = 0; ks < 14; ks += 2) {
        QG_LOAD(ks + 2, pA0, pA1, pB0, pB1)
        GEMM_COMPUTE(0)
        GEMM_STORE(1, qA0, qA1, qB0, qB1)
        __syncthreads();
        QG_LOAD(ks + 3, qA0, qA1, qB0, qB1)
        GEMM_COMPUTE(1)
        GEMM_STORE(0, pA0, pA1, pB0, pB1)
        __syncthreads();
    }
    GEMM_COMPUTE(0)
    GEMM_STORE(1, qA0, qA1, qB0, qB1)
    __syncthreads();
    GEMM_COMPUTE(1)

    float bv[4];
#pragma unroll
    for (int c = 0; c < 4; ++c) bv[c] = bias[n0 + wc * 64 + c * 16 + ln];
#pragma unroll
    for (int r = 0; r < 4; ++r)
#pragma unroll
        for (int c = 0; c < 4; ++c)
#pragma unroll
            for (int q = 0; q < 4; ++q) {
                int row = m0 + wr * 64 + r * 16 + lg * 4 + q;
                int col = n0 + wc * 64 + c * 16 + ln;
                Qb[(size_t)row * 512 + col] = f2bf(acc[r][c][q] + bv[c]);
            }
}

// ---------------- sgemm: P = exp(mask(Q X^T)) packed lower-tri tiles + rowsum->den, depth-2 ---
__global__ __launch_bounds__(256, 2) void sgemm_kernel(const ushort* __restrict__ Qb,
                                                       const ushort* __restrict__ Xb,
                                                       ushort* __restrict__ Pb,
                                                       float* __restrict__ den,
                                                       int g0, int G) {
    __shared__ ushort At[2][128 * 40];
    __shared__ ushort Bt[2][128 * 40];
    int t  = threadIdx.x;
    int bL = blockIdx.x;
    int b  = g0 + bL;
    int c  = blockIdx.y;               // 0..135
    int it = 0, base = 0;
    for (;;) { if (c < base + it + 1) break; base += it + 1; ++it; }
    int jt = c - base;

    int m0 = it << 7, n0 = jt << 7;
    int w  = t >> 6, l = t & 63, ln = l & 15, lg = l >> 4;
    int wr = w >> 1, wc = w & 1;

    const ushort* Arow = Qb + (size_t)(b * SEQ + m0) * 512;
    const ushort* Brow = Xb + (size_t)(b * SEQ + n0) * 512;

    f32x4 acc[4][4] = {};
    int srow = t >> 2;
    int sc8  = (t & 3) * 8;

#define SG_LOAD(KS, A0, A1, B0, B1)                                                \
    A0 = *(const uint4*)(Arow + (size_t)srow * 512 + (KS) * 32 + sc8);             \
    A1 = *(const uint4*)(Arow + (size_t)(64 + srow) * 512 + (KS) * 32 + sc8);      \
    B0 = *(const uint4*)(Brow + (size_t)srow * 512 + (KS) * 32 + sc8);             \
    B1 = *(const uint4*)(Brow + (size_t)(64 + srow) * 512 + (KS) * 32 + sc8);

    uint4 pA0, pA1, pB0, pB1, qA0, qA1, qB0, qB1;
    SG_LOAD(0, pA0, pA1, pB0, pB1)
    SG_LOAD(1, qA0, qA1, qB0, qB1)
    GEMM_STORE(0, pA0, pA1, pB0, pB1)
    __syncthreads();
    for (int ks = 0; ks < 14; ks += 2) {
        SG_LOAD(ks + 2, pA0, pA1, pB0, pB1)
        GEMM_COMPUTE(0)
        GEMM_STORE(1, qA0, qA1, qB0, qB1)
        __syncthreads();
        SG_LOAD(ks + 3, qA0, qA1, qB0, qB1)
        GEMM_COMPUTE(1)
        GEMM_STORE(0, pA0, pA1, pB0, pB1)
        __syncthreads();
    }
    GEMM_COMPUTE(0)
    GEMM_STORE(1, qA0, qA1, qB0, qB1)
    __syncthreads();
    GEMM_COMPUTE(1)

    ushort* ptile = Pb + ((size_t)c * G + bL) * 16384;
#pragma unroll
    for (int r = 0; r < 4; ++r)
#pragma unroll
        for (int q = 0; q < 4; ++q) {
            int row  = wr * 64 + r * 16 + lg * 4 + q;       // local i
            int grow = m0 + row;                            // in-batch i
            float rs = 0.f;
#pragma unroll
            for (int cc = 0; cc < 4; ++cc) {
                int col = n0 + wc * 64 + cc * 16 + ln;      // in-batch j
                float ex = (col < grow) ? __expf(acc[r][cc][q]) : 0.f;
                rs += ex;
                ptile[row * 128 + (wc * 64 + cc * 16 + ln)] = f2bf(ex);
            }
            rs += __shfl_xor(rs, 1);
            rs += __shfl_xor(rs, 2);
            rs += __shfl_xor(rs, 4);
            rs += __shfl_xor(rs, 8);
            if (ln == 0) unsafeAtomicAdd(&den[b * SEQ + grow], rs);
        }
}

// ---------------- pvgemm: out = (P @ X) * 1/(den+1e-10), paired tiles, depth-2 ----------------
// blockIdx.y in [0,64): p = y>>3 -> block does it=15-p then it=p (uniform 68 K-steps);
// ht = y&7 -> 64-col output slice. Full-K ownership, plain stores.
__global__ __launch_bounds__(256, 2) void pvgemm_kernel(const ushort* __restrict__ Pb,
                                                        const ushort* __restrict__ Xt,
                                                        const float* __restrict__ den,
                                                        float* __restrict__ out,
                                                        int g0, int G) {
    __shared__ ushort At[2][128 * 40];
    __shared__ ushort Bt2[2][64 * 40];
    int t  = threadIdx.x;
    int bL = blockIdx.x;
    int b  = g0 + bL;
    int y  = blockIdx.y;
    int p  = y >> 3;                   // 0..7
    int ht = y & 7;                    // 0..7
    int n0 = ht << 6;

    int w = t >> 6, l = t & 63, ln = l & 15, lg = l >> 4;
    int wr = w >> 1, wc = w & 1;       // wave tile: rows wr*64.., cols wc*32..
    int srow = t >> 2;                 // 0..63
    int sc8  = (t & 3) * 8;

    const ushort* BrowX = Xt + ((size_t)b * DIM + n0) * SEQ;

#define PV_LOAD(KK, A0, A1, B0)                                                    \
    {                                                                              \
        const ushort* ptile = Pb + ((size_t)(Tit + ((KK) >> 2)) * G + bL) * 16384  \
                              + ((KK) & 3) * 32;                                   \
        A0 = *(const uint4*)(ptile + srow * 128 + sc8);                            \
        A1 = *(const uint4*)(ptile + (64 + srow) * 128 + sc8);                     \
        B0 = *(const uint4*)(BrowX + (size_t)srow * SEQ + (KK) * 32 + sc8);        \
    }
#define PV_ST(CUR, A0, A1, B0)                              \
    {                                                       \
        *(uint4*)&At[CUR][srow * 40 + sc8]        = A0;     \
        *(uint4*)&At[CUR][(64 + srow) * 40 + sc8] = A1;     \
        *(uint4*)&Bt2[CUR][srow * 40 + sc8]       = B0;     \
    }
#define PV_COMPUTE(CUR)                                                                   \
    {                                                                                     \
        bf16x8 af[4], bfr[2];                                                             \
        _Pragma("unroll") for (int r = 0; r < 4; ++r)                                     \
            af[r] = *(const bf16x8*)&At[CUR][(wr * 64 + r * 16 + ln) * 40 + lg * 8];      \
        _Pragma("unroll") for (int cc = 0; cc < 2; ++cc)                                  \
            bfr[cc] = *(const bf16x8*)&Bt2[CUR][(wc * 32 + cc * 16 + ln) * 40 + lg * 8];  \
        _Pragma("unroll") for (int r = 0; r < 4; ++r)                                     \
            _Pragma("unroll") for (int cc = 0; cc < 2; ++cc)                              \
                acc[r][cc] = __builtin_amdgcn_mfma_f32_16x16x32_bf16(af[r], bfr[cc],      \
                                                                     acc[r][cc], 0, 0, 0);\
    }

    for (int half = 0; half < 2; ++half) {
        int it  = half ? p : (15 - p);
        int Tit = (it * (it + 1)) >> 1;
        int n   = (it + 1) * 4;
        int m0  = it << 7;
        f32x4 acc[4][2] = {};

        uint4 pA0, pA1, pB0, qA0, qA1, qB0;
        PV_LOAD(0, pA0, pA1, pB0)
        PV_LOAD(1, qA0, qA1, qB0)
        __syncthreads();               // prev half's readers done (no-op for half 0)
        PV_ST(0, pA0, pA1, pB0)
        __syncthreads();
        for (int ks = 0; ks < n - 2; ks += 2) {
            PV_LOAD(ks + 2, pA0, pA1, pB0)
            PV_COMPUTE(0)
            PV_ST(1, qA0, qA1, qB0)
            __syncthreads();
            if (ks + 3 < n) PV_LOAD(ks + 3, qA0, qA1, qB0)
            PV_COMPUTE(1)
            PV_ST(0, pA0, pA1, pB0)
            __syncthreads();
        }
        PV_COMPUTE(0)
        PV_ST(1, qA0, qA1, qB0)
        __syncthreads();
        PV_COMPUTE(1)

#pragma unroll
        for (int r = 0; r < 4; ++r)
#pragma unroll
            for (int q = 0; q < 4; ++q) {
                int row = m0 + wr * 64 + r * 16 + lg * 4 + q;
                float inv = 1.0f / (den[b * SEQ + row] + 1e-10f);
                size_t o = (size_t)(b * SEQ + row) * 512;
#pragma unroll
                for (int cc = 0; cc < 2; ++cc)
                    out[o + n0 + wc * 32 + cc * 16 + ln] = acc[r][cc][q] * inv;
            }
    }
}

extern "C" void kernel_launch(void* const* d_in, const int* in_sizes, int n_in,
                              void* d_out, int out_size, void* d_ws, size_t ws_size,
                              hipStream_t stream) {
    const float* X    = (const float*)d_in[0];
    const float* W    = (const float*)d_in[1];
    const float* bias = (const float*)d_in[2];
    float* out = (float*)d_out;

    // ws layout (bytes): Xb[16.78M] | Xt[16.78M] | Qb[16.78M] | Wb[0.52M] | den[64K] | Pb[G*4.46M]
    ushort* ws = (ushort*)d_ws;
    ushort* Xb = ws;
    ushort* Xt = ws + 8388608;
    ushort* Qb = ws + 16777216;
    ushort* Wb = ws + 25165824;
    float*  den = (float*)((char*)d_ws + 50855936);
    ushort* Pb = (ushort*)((char*)d_ws + 50921472);

    // batch-group size: largest pow2 G<=8 with Pb (G*4,456,448 B) fitting in remaining ws
    size_t avail = (ws_size > 50921472) ? (ws_size - 50921472) : 0;
    int G = 1;
    while (G < 8 && (size_t)(G * 2) * 4456448 <= avail) G *= 2;

    hipMemsetAsync(den, 0, (size_t)BATCH * SEQ * sizeof(float), stream);
    prep_kernel<<<dim3(8192), dim3(256), 0, stream>>>(X, Xb, Xt);
    wconv_kernel<<<dim3(128), dim3(256), 0, stream>>>(W, Wb);
    qgemm_kernel<<<dim3(512), dim3(256), 0, stream>>>(Xb, Wb, bias, Qb);
    for (int g0 = 0; g0 < BATCH; g0 += G) {
        sgemm_kernel<<<dim3(G, 136), dim3(256), 0, stream>>>(Qb, Xb, Pb, den, g0, G);
        pvgemm_kernel<<<dim3(G, 64), dim3(256), 0, stream>>>(Pb, Xt, den, out, g0, G);
    }
}